// Round 9
// baseline (1025.404 us; speedup 1.0000x reference)
//
#include <hip/hip_runtime.h>
#include <hip/hip_bf16.h>

#define CDIM 64
#define KCODES 512
#define HWD 4096          // H*W
#define NPIX 131072       // B*H*W
#define NELEM 8388608     // B*C*H*W
#define BLK 128           // 2 waves; block tile = 128 px x 512 codes
#define EST 68            // padded LDS row stride in floats (16B-aligned, banks spread)
// out layout (fp32 elements): [0]=loss, [1..1+NELEM)=quantized,
// then enc_idx(NPIX), perplexity(1), codes(NPIX)
#define OFF_Q 1
#define OFF_ENC (1 + NELEM)
#define OFF_PERP (1 + NELEM + NPIX)
#define OFF_CODES (1 + NELEM + NPIX + 1)

// numpy pairwise combine of 8 partials
__device__ __forceinline__ float np_pairwise_combine8(const float* r) {
    float s01 = __fadd_rn(r[0], r[1]);
    float s23 = __fadd_rn(r[2], r[3]);
    float s45 = __fadd_rn(r[4], r[5]);
    float s67 = __fadd_rn(r[6], r[7]);
    return __fadd_rn(__fadd_rn(s01, s23), __fadd_rn(s45, s67));
}

__device__ __forceinline__ float np_pairwise_sq64(const float* v) {
    float r[8];
    #pragma unroll
    for (int j = 0; j < 8; ++j) r[j] = __fmul_rn(v[j], v[j]);
    #pragma unroll
    for (int i = 8; i < 64; i += 8) {
        #pragma unroll
        for (int j = 0; j < 8; ++j) r[j] = __fadd_rn(r[j], __fmul_rn(v[i + j], v[i + j]));
    }
    return np_pairwise_combine8(r);
}

// ws float layout: [0]=loss_acc, [64..576)=counts, [576..1088)=ee
__global__ void ee_kernel(const float* __restrict__ e, float* __restrict__ ee) {
    int k = blockIdx.x * blockDim.x + threadIdx.x;
    if (k < KCODES) {
        float v[CDIM];
        #pragma unroll
        for (int c = 0; c < CDIM; ++c) v[c] = e[k * CDIM + c];
        ee[k] = np_pairwise_sq64(v);
    }
}

// Rounds 4-7 plateaued at 38-46% VALU: 1 e-operand per FMA, no temporal
// reuse — neither K$ (latency) nor LDS broadcast (bus: 1024B/instr) can
// deliver at that ratio. Fix: 8px x 8codes register micro-tile per thread:
// 16 ds_read_b128 per 256 FMAs (8x less operand traffic). Codes on tid&7,
// pixels on tid>>3. e k-group (16KB) double-buffered in LDS, loads issued
// before compute (T14). Distance chains instruction-identical to the
// verified numerics: sequential c-ascending __fmaf_rn per (px,k), pairwise-8
// xx/ee, (xx+ee)-2d combine, first-occurrence argmin (strict < ascending k,
// cross-lane lexicographic (d,idx) reduce).
__launch_bounds__(BLK, 1)
__global__ void vq_main(const float* __restrict__ in, const float* __restrict__ e,
                        const float* __restrict__ ee, float* __restrict__ loss_acc,
                        float* __restrict__ counts, float* __restrict__ out) {
    __shared__ float xls[BLK * EST];       // 34816 B: x[128px][64c], stride 68
    __shared__ float els[2][64 * EST];     // 2x17408 B: e k-group double buffer
    __shared__ float xxls[BLK];
    __shared__ float eels[KCODES];

    int tid = threadIdx.x;
    int p0 = blockIdx.x * BLK;
    int b = p0 >> 12;
    int hw0 = p0 & (HWD - 1);

    const float* xin = in + (size_t)b * CDIM * HWD + hw0 + tid;

    // stage x (c by 4, b128 writes) + xx (numpy pairwise-8 of rounded squares)
    float r[8];
    #pragma unroll
    for (int t = 0; t < 16; ++t) {
        float v0 = xin[(size_t)(4 * t + 0) * HWD];
        float v1 = xin[(size_t)(4 * t + 1) * HWD];
        float v2 = xin[(size_t)(4 * t + 2) * HWD];
        float v3 = xin[(size_t)(4 * t + 3) * HWD];
        int j = (t & 1) * 4;
        if (t < 2) {
            r[j + 0] = __fmul_rn(v0, v0); r[j + 1] = __fmul_rn(v1, v1);
            r[j + 2] = __fmul_rn(v2, v2); r[j + 3] = __fmul_rn(v3, v3);
        } else {
            r[j + 0] = __fadd_rn(r[j + 0], __fmul_rn(v0, v0));
            r[j + 1] = __fadd_rn(r[j + 1], __fmul_rn(v1, v1));
            r[j + 2] = __fadd_rn(r[j + 2], __fmul_rn(v2, v2));
            r[j + 3] = __fadd_rn(r[j + 3], __fmul_rn(v3, v3));
        }
        *reinterpret_cast<float4*>(&xls[tid * EST + 4 * t]) = make_float4(v0, v1, v2, v3);
    }
    xxls[tid] = np_pairwise_combine8(r);
    for (int i = tid; i < KCODES; i += BLK) eels[i] = ee[i];
    // stage e k-group 0 (coalesced float4; LDS layout row*EST + c)
    #pragma unroll
    for (int u = 0; u < 8; ++u) {
        int f = tid + BLK * u;                       // float4 index in 64x64 tile
        float4 v = reinterpret_cast<const float4*>(e)[f];
        *reinterpret_cast<float4*>(&els[0][(f >> 4) * EST + (f & 15) * 4]) = v;
    }
    __syncthreads();

    float xxv[8];
    #pragma unroll
    for (int j = 0; j < 8; ++j) xxv[j] = xxls[(tid >> 3) + 16 * j];

    float dmin[8]; int idxv[8];
    #pragma unroll
    for (int j = 0; j < 8; ++j) { dmin[j] = 3.4e38f; idxv[j] = 0; }

    for (int kg = 0; kg < 8; ++kg) {
        int cur = kg & 1;
        float4 pf[8];
        if (kg < 7) {   // issue next k-group's global loads BEFORE compute
            const float4* src = reinterpret_cast<const float4*>(e + (size_t)(kg + 1) * 4096);
            #pragma unroll
            for (int u = 0; u < 8; ++u) pf[u] = src[tid + BLK * u];
        }
        float acc[8][8];
        #pragma unroll
        for (int j = 0; j < 8; ++j)
            #pragma unroll
            for (int i = 0; i < 8; ++i) acc[j][i] = 0.f;

        const float* eb = els[cur];
        #pragma unroll
        for (int cb = 0; cb < CDIM; cb += 4) {
            float4 xv[8], ev[8];
            #pragma unroll
            for (int j = 0; j < 8; ++j)
                xv[j] = *reinterpret_cast<const float4*>(&xls[((tid >> 3) + 16 * j) * EST + cb]);
            #pragma unroll
            for (int i = 0; i < 8; ++i)
                ev[i] = *reinterpret_cast<const float4*>(&eb[((tid & 7) + 8 * i) * EST + cb]);
            #pragma unroll
            for (int j = 0; j < 8; ++j) {
                #pragma unroll
                for (int i = 0; i < 8; ++i) {
                    // c-ascending sequential chain: x->y->z->w
                    acc[j][i] = __fmaf_rn(xv[j].w, ev[i].w,
                                __fmaf_rn(xv[j].z, ev[i].z,
                                __fmaf_rn(xv[j].y, ev[i].y,
                                __fmaf_rn(xv[j].x, ev[i].x, acc[j][i]))));
                }
            }
        }
        int k0 = kg * 64 + (tid & 7);
        #pragma unroll
        for (int i = 0; i < 8; ++i) {       // i ascending => k ascending per thread
            float eei = eels[k0 + 8 * i];
            #pragma unroll
            for (int j = 0; j < 8; ++j) {
                float dd = __fsub_rn(__fadd_rn(xxv[j], eei), __fmul_rn(2.f, acc[j][i]));
                if (dd < dmin[j]) { dmin[j] = dd; idxv[j] = k0 + 8 * i; }
            }
        }
        if (kg < 7) {   // write next k-group into the other buffer (vmcnt lands here)
            #pragma unroll
            for (int u = 0; u < 8; ++u) {
                int f = tid + BLK * u;
                *reinterpret_cast<float4*>(&els[cur ^ 1][(f >> 4) * EST + (f & 15) * 4]) = pf[u];
            }
        }
        __syncthreads();
    }

    // cross-lane argmin over the 8 lanes_k (tid bits 0-2), first-occurrence ties
    #pragma unroll
    for (int j = 0; j < 8; ++j) {
        float d = dmin[j]; int ix = idxv[j];
        #pragma unroll
        for (int s = 1; s < 8; s <<= 1) {
            float od = __shfl_xor(d, s, 64);
            int oi = __shfl_xor(ix, s, 64);
            if (od < d || (od == d && oi < ix)) { d = od; ix = oi; }
        }
        idxv[j] = ix;
    }

    // outputs: each lane handles its 8 px over c-slice (tid&7)*8..+7
    int cs = (tid & 7) * 8;
    float lsum = 0.f;
    #pragma unroll
    for (int j = 0; j < 8; ++j) {
        int px = (tid >> 3) + 16 * j;
        int ix = idxv[j];
        const float4* eg = reinterpret_cast<const float4*>(e + (size_t)ix * CDIM + cs);
        float4 q0 = eg[0], q1 = eg[1];
        const float* xr = &xls[px * EST + cs];
        float* oq = out + OFF_Q + (size_t)b * CDIM * HWD + hw0 + px;
        oq[(size_t)(cs + 0) * HWD] = q0.x;
        oq[(size_t)(cs + 1) * HWD] = q0.y;
        oq[(size_t)(cs + 2) * HWD] = q0.z;
        oq[(size_t)(cs + 3) * HWD] = q0.w;
        oq[(size_t)(cs + 4) * HWD] = q1.x;
        oq[(size_t)(cs + 5) * HWD] = q1.y;
        oq[(size_t)(cs + 6) * HWD] = q1.z;
        oq[(size_t)(cs + 7) * HWD] = q1.w;
        float t;
        t = q0.x - xr[0]; lsum = __fmaf_rn(t, t, lsum);
        t = q0.y - xr[1]; lsum = __fmaf_rn(t, t, lsum);
        t = q0.z - xr[2]; lsum = __fmaf_rn(t, t, lsum);
        t = q0.w - xr[3]; lsum = __fmaf_rn(t, t, lsum);
        t = q1.x - xr[4]; lsum = __fmaf_rn(t, t, lsum);
        t = q1.y - xr[5]; lsum = __fmaf_rn(t, t, lsum);
        t = q1.z - xr[6]; lsum = __fmaf_rn(t, t, lsum);
        t = q1.w - xr[7]; lsum = __fmaf_rn(t, t, lsum);
    }
    if ((tid & 7) == 0) {
        #pragma unroll
        for (int j = 0; j < 8; ++j) {
            int px = (tid >> 3) + 16 * j;
            float fidx = (float)idxv[j];
            out[OFF_ENC + p0 + px] = fidx;
            out[OFF_CODES + p0 + px] = fidx;
            atomicAdd(&counts[idxv[j]], 1.0f);
        }
    }
    #pragma unroll
    for (int off = 32; off > 0; off >>= 1) lsum += __shfl_down(lsum, off, 64);
    if ((tid & 63) == 0) atomicAdd(loss_acc, lsum);
}

__global__ void finalize_kernel(const float* __restrict__ loss_acc,
                                const float* __restrict__ counts,
                                float* __restrict__ out) {
    __shared__ float red[8];
    int t = threadIdx.x;  // 512 threads
    float pr = counts[t] * (1.0f / (float)NPIX);
    float term = pr * logf(pr + 1e-10f);
    #pragma unroll
    for (int off = 32; off > 0; off >>= 1) term += __shfl_down(term, off, 64);
    if ((t & 63) == 0) red[t >> 6] = term;
    __syncthreads();
    if (t == 0) {
        float s = 0.f;
        #pragma unroll
        for (int i = 0; i < 8; ++i) s += red[i];
        out[OFF_PERP] = expf(-s);
        out[0] = 0.25f * loss_acc[0] * (1.0f / (float)NELEM);
    }
}

extern "C" void kernel_launch(void* const* d_in, const int* in_sizes, int n_in,
                              void* d_out, int out_size, void* d_ws, size_t ws_size,
                              hipStream_t stream) {
    const float* in = (const float*)d_in[0];
    const float* e = (const float*)d_in[1];
    float* out = (float*)d_out;
    float* wsf = (float*)d_ws;
    float* loss_acc = wsf + 0;
    float* counts = wsf + 64;
    float* ee = wsf + 576;

    hipMemsetAsync(d_ws, 0, 2304, stream);  // loss_acc + counts
    ee_kernel<<<1, 512, 0, stream>>>(e, ee);
    vq_main<<<NPIX / BLK, BLK, 0, stream>>>(in, e, ee, loss_acc, counts, out);
    finalize_kernel<<<1, 512, 0, stream>>>(loss_acc, counts, out);
}

// Round 11
// 348.861 us; speedup vs baseline: 2.9393x; 2.9393x over previous
//
#include <hip/hip_runtime.h>
#include <hip/hip_bf16.h>

#define CDIM 64
#define KCODES 512
#define HWD 4096          // H*W
#define NPIX 131072       // B*H*W
#define NELEM 8388608     // B*C*H*W
#define BLK 128           // 2 waves; block tile = 128 px x 512 codes
#define EST 68            // padded x-LDS row stride (16B-aligned, 4-way banks max)
// out layout (fp32 elements): [0]=loss, [1..1+NELEM)=quantized,
// then enc_idx(NPIX), perplexity(1), codes(NPIX)
#define OFF_Q 1
#define OFF_ENC (1 + NELEM)
#define OFF_PERP (1 + NELEM + NPIX)
#define OFF_CODES (1 + NELEM + NPIX + 1)

// numpy pairwise combine of 8 partials
__device__ __forceinline__ float np_pairwise_combine8(const float* r) {
    float s01 = __fadd_rn(r[0], r[1]);
    float s23 = __fadd_rn(r[2], r[3]);
    float s45 = __fadd_rn(r[4], r[5]);
    float s67 = __fadd_rn(r[6], r[7]);
    return __fadd_rn(__fadd_rn(s01, s23), __fadd_rn(s45, s67));
}

__device__ __forceinline__ float np_pairwise_sq64(const float* v) {
    float r[8];
    #pragma unroll
    for (int j = 0; j < 8; ++j) r[j] = __fmul_rn(v[j], v[j]);
    #pragma unroll
    for (int i = 8; i < 64; i += 8) {
        #pragma unroll
        for (int j = 0; j < 8; ++j) r[j] = __fadd_rn(r[j], __fmul_rn(v[i + j], v[i + j]));
    }
    return np_pairwise_combine8(r);
}

// async global->LDS, 16B per lane, zero VGPR cost for the data
__device__ __forceinline__ void gll16(const void* g, void* l) {
    __builtin_amdgcn_global_load_lds(
        (const __attribute__((address_space(1))) unsigned int*)g,
        (__attribute__((address_space(3))) unsigned int*)l, 16, 0, 0);
}

// ws float layout: [0]=loss_acc, [64..576)=counts, [576..1088)=ee
__global__ void ee_kernel(const float* __restrict__ e, float* __restrict__ ee) {
    int k = blockIdx.x * blockDim.x + threadIdx.x;
    if (k < KCODES) {
        float v[CDIM];
        #pragma unroll
        for (int c = 0; c < CDIM; ++c) v[c] = e[k * CDIM + c];
        ee[k] = np_pairwise_sq64(v);
    }
}

// Round 9 (same tile, reg-prefetch + ds_write staging) spilled: 256 VGPR cap,
// 3.9GB scratch traffic, VALU 13%. This version is arithmetically identical
// but drops ~90 live VGPRs: e staged via global_load_lds (no pf[8] regs, no
// ds_writes), ev loaded one-at-a-time inside the i-loop (liveness 32->4).
// e LDS is linear with a chunk-XOR swizzle (pos = q ^ (row&7)) applied to the
// PRE-SWIZZLED GLOBAL SOURCE (global_load_lds writes linearly; rule: same
// involution on source and read) -> conflict-free ds_read_b128 on e rows.
__launch_bounds__(BLK, 1)
__global__ void vq_main(const float* __restrict__ in, const float* __restrict__ e,
                        const float* __restrict__ ee, float* __restrict__ loss_acc,
                        float* __restrict__ counts, float* __restrict__ out) {
    __shared__ float xls[BLK * EST];       // 34816 B: x[128px][64c], stride 68
    __shared__ float els[2][64 * 64];      // 2x16384 B: e k-group, linear+XOR chunks
    __shared__ float xxls[BLK];
    __shared__ float eels[KCODES];

    int tid = threadIdx.x;
    int p0 = blockIdx.x * BLK;
    int b = p0 >> 12;
    int hw0 = p0 & (HWD - 1);

    const float* xin = in + (size_t)b * CDIM * HWD + hw0 + tid;

    // stage x (c by 4) + xx (numpy pairwise-8 of rounded squares) — verified r4/r9
    float r[8];
    #pragma unroll
    for (int t = 0; t < 16; ++t) {
        float v0 = xin[(size_t)(4 * t + 0) * HWD];
        float v1 = xin[(size_t)(4 * t + 1) * HWD];
        float v2 = xin[(size_t)(4 * t + 2) * HWD];
        float v3 = xin[(size_t)(4 * t + 3) * HWD];
        int j = (t & 1) * 4;
        if (t < 2) {
            r[j + 0] = __fmul_rn(v0, v0); r[j + 1] = __fmul_rn(v1, v1);
            r[j + 2] = __fmul_rn(v2, v2); r[j + 3] = __fmul_rn(v3, v3);
        } else {
            r[j + 0] = __fadd_rn(r[j + 0], __fmul_rn(v0, v0));
            r[j + 1] = __fadd_rn(r[j + 1], __fmul_rn(v1, v1));
            r[j + 2] = __fadd_rn(r[j + 2], __fmul_rn(v2, v2));
            r[j + 3] = __fadd_rn(r[j + 3], __fmul_rn(v3, v3));
        }
        *reinterpret_cast<float4*>(&xls[tid * EST + 4 * t]) = make_float4(v0, v1, v2, v3);
    }
    xxls[tid] = np_pairwise_combine8(r);
    for (int i = tid; i < KCODES; i += BLK) eels[i] = ee[i];

    // stage e k-group kg into els[buf]: LDS chunk l holds global chunk
    // g = (l&~7) | ((l ^ (l>>4)) & 7)   (involution: pos ^= row&7)
    #define STAGE_E(buf, kg)                                                   \
        {                                                                      \
            const char* gb = (const char*)(e + (size_t)(kg) * 4096);           \
            char* lb = (char*)&els[buf][0] + (size_t)(tid & ~63) * 16;         \
            _Pragma("unroll")                                                  \
            for (int u = 0; u < 8; ++u) {                                      \
                int l = tid + 128 * u;                                         \
                int g = (l & ~7) | ((l ^ (l >> 4)) & 7);                       \
                gll16(gb + (size_t)g * 16, lb + (size_t)(128 * u) * 16);       \
            }                                                                  \
        }

    STAGE_E(0, 0);
    __syncthreads();   // drains vmcnt -> group 0 resident

    float xxv[8];
    #pragma unroll
    for (int j = 0; j < 8; ++j) xxv[j] = xxls[(tid >> 3) + 16 * j];

    float dmin[8]; int idxv[8];
    #pragma unroll
    for (int j = 0; j < 8; ++j) { dmin[j] = 3.4e38f; idxv[j] = 0; }

    for (int kg = 0; kg < 8; ++kg) {
        int cur = kg & 1;
        if (kg < 7) STAGE_E(cur ^ 1, kg + 1);   // async, lands before bottom barrier

        float acc[8][8];
        #pragma unroll
        for (int j = 0; j < 8; ++j)
            #pragma unroll
            for (int i = 0; i < 8; ++i) acc[j][i] = 0.f;

        const float* eb = els[cur];
        #pragma unroll
        for (int cb = 0; cb < CDIM; cb += 4) {
            int q = cb >> 2;
            float4 xv[8];
            #pragma unroll
            for (int j = 0; j < 8; ++j)
                xv[j] = *reinterpret_cast<const float4*>(&xls[((tid >> 3) + 16 * j) * EST + cb]);
            // swizzled chunk position for this column, same for all 8 rows of this lane
            int ep = ((((q ^ (tid & 7)) & 7) | (q & 8)) << 2) + (tid & 7) * 64;
            #pragma unroll
            for (int i = 0; i < 8; ++i) {
                float4 ev = *reinterpret_cast<const float4*>(&eb[ep + 512 * i]);
                #pragma unroll
                for (int j = 0; j < 8; ++j) {
                    // c-ascending sequential chain: x->y->z->w (verified numerics)
                    acc[j][i] = __fmaf_rn(xv[j].w, ev.w,
                                __fmaf_rn(xv[j].z, ev.z,
                                __fmaf_rn(xv[j].y, ev.y,
                                __fmaf_rn(xv[j].x, ev.x, acc[j][i]))));
                }
            }
        }
        int k0 = kg * 64 + (tid & 7);
        #pragma unroll
        for (int i = 0; i < 8; ++i) {       // i ascending => k ascending per thread
            float eei = eels[k0 + 8 * i];
            #pragma unroll
            for (int j = 0; j < 8; ++j) {
                float dd = __fsub_rn(__fadd_rn(xxv[j], eei), __fmul_rn(2.f, acc[j][i]));
                if (dd < dmin[j]) { dmin[j] = dd; idxv[j] = k0 + 8 * i; }
            }
        }
        __syncthreads();   // drains gll vmcnt + releases buffer cur
    }

    // cross-lane argmin over the 8 lanes_k (tid bits 0-2), first-occurrence ties
    #pragma unroll
    for (int j = 0; j < 8; ++j) {
        float d = dmin[j]; int ix = idxv[j];
        #pragma unroll
        for (int s = 1; s < 8; s <<= 1) {
            float od = __shfl_xor(d, s, 64);
            int oi = __shfl_xor(ix, s, 64);
            if (od < d || (od == d && oi < ix)) { d = od; ix = oi; }
        }
        idxv[j] = ix;
    }

    // outputs: each lane handles its 8 px over c-slice (tid&7)*8..+7
    int cs = (tid & 7) * 8;
    float lsum = 0.f;
    #pragma unroll
    for (int j = 0; j < 8; ++j) {
        int px = (tid >> 3) + 16 * j;
        int ix = idxv[j];
        const float4* eg = reinterpret_cast<const float4*>(e + (size_t)ix * CDIM + cs);
        float4 q0 = eg[0], q1 = eg[1];
        const float* xr = &xls[px * EST + cs];
        float* oq = out + OFF_Q + (size_t)b * CDIM * HWD + hw0 + px;
        oq[(size_t)(cs + 0) * HWD] = q0.x;
        oq[(size_t)(cs + 1) * HWD] = q0.y;
        oq[(size_t)(cs + 2) * HWD] = q0.z;
        oq[(size_t)(cs + 3) * HWD] = q0.w;
        oq[(size_t)(cs + 4) * HWD] = q1.x;
        oq[(size_t)(cs + 5) * HWD] = q1.y;
        oq[(size_t)(cs + 6) * HWD] = q1.z;
        oq[(size_t)(cs + 7) * HWD] = q1.w;
        float t;
        t = q0.x - xr[0]; lsum = __fmaf_rn(t, t, lsum);
        t = q0.y - xr[1]; lsum = __fmaf_rn(t, t, lsum);
        t = q0.z - xr[2]; lsum = __fmaf_rn(t, t, lsum);
        t = q0.w - xr[3]; lsum = __fmaf_rn(t, t, lsum);
        t = q1.x - xr[4]; lsum = __fmaf_rn(t, t, lsum);
        t = q1.y - xr[5]; lsum = __fmaf_rn(t, t, lsum);
        t = q1.z - xr[6]; lsum = __fmaf_rn(t, t, lsum);
        t = q1.w - xr[7]; lsum = __fmaf_rn(t, t, lsum);
    }
    if ((tid & 7) == 0) {
        #pragma unroll
        for (int j = 0; j < 8; ++j) {
            int px = (tid >> 3) + 16 * j;
            float fidx = (float)idxv[j];
            out[OFF_ENC + p0 + px] = fidx;
            out[OFF_CODES + p0 + px] = fidx;
            atomicAdd(&counts[idxv[j]], 1.0f);
        }
    }
    #pragma unroll
    for (int off = 32; off > 0; off >>= 1) lsum += __shfl_down(lsum, off, 64);
    if ((tid & 63) == 0) atomicAdd(loss_acc, lsum);
}

__global__ void finalize_kernel(const float* __restrict__ loss_acc,
                                const float* __restrict__ counts,
                                float* __restrict__ out) {
    __shared__ float red[8];
    int t = threadIdx.x;  // 512 threads
    float pr = counts[t] * (1.0f / (float)NPIX);
    float term = pr * logf(pr + 1e-10f);
    #pragma unroll
    for (int off = 32; off > 0; off >>= 1) term += __shfl_down(term, off, 64);
    if ((t & 63) == 0) red[t >> 6] = term;
    __syncthreads();
    if (t == 0) {
        float s = 0.f;
        #pragma unroll
        for (int i = 0; i < 8; ++i) s += red[i];
        out[OFF_PERP] = expf(-s);
        out[0] = 0.25f * loss_acc[0] * (1.0f / (float)NELEM);
    }
}

extern "C" void kernel_launch(void* const* d_in, const int* in_sizes, int n_in,
                              void* d_out, int out_size, void* d_ws, size_t ws_size,
                              hipStream_t stream) {
    const float* in = (const float*)d_in[0];
    const float* e = (const float*)d_in[1];
    float* out = (float*)d_out;
    float* wsf = (float*)d_ws;
    float* loss_acc = wsf + 0;
    float* counts = wsf + 64;
    float* ee = wsf + 576;

    hipMemsetAsync(d_ws, 0, 2304, stream);  // loss_acc + counts
    ee_kernel<<<1, 512, 0, stream>>>(e, ee);
    vq_main<<<NPIX / BLK, BLK, 0, stream>>>(in, e, ee, loss_acc, counts, out);
    finalize_kernel<<<1, 512, 0, stream>>>(loss_acc, counts, out);
}

// Round 14
// 285.632 us; speedup vs baseline: 3.5899x; 1.2214x over previous
//
#include <hip/hip_runtime.h>
#include <hip/hip_bf16.h>

#define CDIM 64
#define KCODES 512
#define HWD 4096          // H*W
#define NPIX 131072       // B*H*W
#define NELEM 8388608     // B*C*H*W
#define BLK 256           // 4 waves; block tile = 128 px x 512 codes (4px x 8codes/thread)
#define PXB 128           // pixels per block
#define EST 68            // padded x-LDS row stride
// out layout (fp32 elements): [0]=loss, [1..1+NELEM)=quantized,
// then enc_idx(NPIX), perplexity(1), codes(NPIX)
#define OFF_Q 1
#define OFF_ENC (1 + NELEM)
#define OFF_PERP (1 + NELEM + NPIX)
#define OFF_CODES (1 + NELEM + NPIX + 1)

// numpy pairwise combine of 8 partials
__device__ __forceinline__ float np_pairwise_combine8(const float* r) {
    float s01 = __fadd_rn(r[0], r[1]);
    float s23 = __fadd_rn(r[2], r[3]);
    float s45 = __fadd_rn(r[4], r[5]);
    float s67 = __fadd_rn(r[6], r[7]);
    return __fadd_rn(__fadd_rn(s01, s23), __fadd_rn(s45, s67));
}

__device__ __forceinline__ float np_pairwise_sq64(const float* v) {
    float r[8];
    #pragma unroll
    for (int j = 0; j < 8; ++j) r[j] = __fmul_rn(v[j], v[j]);
    #pragma unroll
    for (int i = 8; i < 64; i += 8) {
        #pragma unroll
        for (int j = 0; j < 8; ++j) r[j] = __fadd_rn(r[j], __fmul_rn(v[i + j], v[i + j]));
    }
    return np_pairwise_combine8(r);
}

// async global->LDS, 16B per lane, zero VGPR cost for the data
__device__ __forceinline__ void gll16(const void* g, void* l) {
    __builtin_amdgcn_global_load_lds(
        (const __attribute__((address_space(1))) unsigned int*)g,
        (__attribute__((address_space(3))) unsigned int*)l, 16, 0, 0);
}

// ws float layout: [0]=loss_acc, [64..576)=counts, [576..1088)=ee
__global__ void ee_kernel(const float* __restrict__ e, float* __restrict__ ee) {
    int k = blockIdx.x * blockDim.x + threadIdx.x;
    if (k < KCODES) {
        float v[CDIM];
        #pragma unroll
        for (int c = 0; c < CDIM; ++c) v[c] = e[k * CDIM + c];
        ee[k] = np_pairwise_sq64(v);
    }
}

// R11: correct + no spills but 1 wave/SIMD (LDS 70KB -> 2 blk/CU x 2 waves)
// and VGPR pressure 132 pinned the scheduler -> serialized ev-load/FMA chain,
// VALU 41%. This round: same 128px x 512codes block tile on 256 threads
// (4px x 8codes micro-tile): 2 waves/SIMD + live set ~90 VGPR so the
// scheduler can hoist ds_reads. Arithmetic chains per (px,k) are
// instruction-identical to the verified r9/r11 numerics.
__launch_bounds__(BLK, 1)
__global__ void vq_main(const float* __restrict__ in, const float* __restrict__ e,
                        const float* __restrict__ ee, float* __restrict__ loss_acc,
                        float* __restrict__ counts, float* __restrict__ out) {
    __shared__ float xls[PXB * EST];       // 34816 B
    __shared__ float els[2][64 * 64];      // 2x16384 B: e k-group, linear+XOR chunks
    __shared__ float xxls[PXB];
    __shared__ float eels[KCODES];

    int tid = threadIdx.x;
    int p0 = blockIdx.x * PXB;
    int b = p0 >> 12;
    int hw0 = p0 & (HWD - 1);

    // stage x + xx: threads 0..127 each own one px (identical sequence to r11)
    if (tid < PXB) {
        const float* xin = in + (size_t)b * CDIM * HWD + hw0 + tid;
        float r[8];
        #pragma unroll
        for (int t = 0; t < 16; ++t) {
            float v0 = xin[(size_t)(4 * t + 0) * HWD];
            float v1 = xin[(size_t)(4 * t + 1) * HWD];
            float v2 = xin[(size_t)(4 * t + 2) * HWD];
            float v3 = xin[(size_t)(4 * t + 3) * HWD];
            int j = (t & 1) * 4;
            if (t < 2) {
                r[j + 0] = __fmul_rn(v0, v0); r[j + 1] = __fmul_rn(v1, v1);
                r[j + 2] = __fmul_rn(v2, v2); r[j + 3] = __fmul_rn(v3, v3);
            } else {
                r[j + 0] = __fadd_rn(r[j + 0], __fmul_rn(v0, v0));
                r[j + 1] = __fadd_rn(r[j + 1], __fmul_rn(v1, v1));
                r[j + 2] = __fadd_rn(r[j + 2], __fmul_rn(v2, v2));
                r[j + 3] = __fadd_rn(r[j + 3], __fmul_rn(v3, v3));
            }
            *reinterpret_cast<float4*>(&xls[tid * EST + 4 * t]) = make_float4(v0, v1, v2, v3);
        }
        xxls[tid] = np_pairwise_combine8(r);
    }
    for (int i = tid; i < KCODES; i += BLK) eels[i] = ee[i];

    // stage e k-group kg into els[buf]: LDS chunk l holds global chunk
    // g = (l&~7) | ((l ^ (l>>4)) & 7)   (involution: pos ^= row&7); 256 thr x 4
    #define STAGE_E(buf, kg)                                                   \
        {                                                                      \
            const char* gb = (const char*)(e + (size_t)(kg) * 4096);           \
            char* lb = (char*)&els[buf][0] + (size_t)(tid & ~63) * 16;         \
            _Pragma("unroll")                                                  \
            for (int u = 0; u < 4; ++u) {                                      \
                int l = tid + 256 * u;                                         \
                int g = (l & ~7) | ((l ^ (l >> 4)) & 7);                       \
                gll16(gb + (size_t)g * 16, lb + (size_t)(256 * u) * 16);       \
            }                                                                  \
        }

    STAGE_E(0, 0);
    __syncthreads();   // drains vmcnt -> group 0 resident

    float xxv[4];
    #pragma unroll
    for (int j = 0; j < 4; ++j) xxv[j] = xxls[(tid >> 3) + 32 * j];

    float dmin[4]; int idxv[4];
    #pragma unroll
    for (int j = 0; j < 4; ++j) { dmin[j] = 3.4e38f; idxv[j] = 0; }

    for (int kg = 0; kg < 8; ++kg) {
        int cur = kg & 1;
        if (kg < 7) STAGE_E(cur ^ 1, kg + 1);   // async, lands before bottom barrier

        float acc[4][8];
        #pragma unroll
        for (int j = 0; j < 4; ++j)
            #pragma unroll
            for (int i = 0; i < 8; ++i) acc[j][i] = 0.f;

        const float* eb = els[cur];
        #pragma unroll
        for (int cb = 0; cb < CDIM; cb += 4) {
            int q = cb >> 2;
            float4 xv[4];
            #pragma unroll
            for (int j = 0; j < 4; ++j)
                xv[j] = *reinterpret_cast<const float4*>(&xls[((tid >> 3) + 32 * j) * EST + cb]);
            // swizzled chunk position for this column (same for all 8 rows of this lane)
            int ep = ((((q ^ (tid & 7)) & 7) | (q & 8)) << 2) + (tid & 7) * 64;
            #pragma unroll
            for (int i = 0; i < 8; ++i) {
                float4 ev = *reinterpret_cast<const float4*>(&eb[ep + 512 * i]);
                #pragma unroll
                for (int j = 0; j < 4; ++j) {
                    // c-ascending sequential chain: x->y->z->w (verified numerics)
                    acc[j][i] = __fmaf_rn(xv[j].w, ev.w,
                                __fmaf_rn(xv[j].z, ev.z,
                                __fmaf_rn(xv[j].y, ev.y,
                                __fmaf_rn(xv[j].x, ev.x, acc[j][i]))));
                }
            }
        }
        int k0 = kg * 64 + (tid & 7);
        #pragma unroll
        for (int i = 0; i < 8; ++i) {       // i ascending => k ascending per thread
            float eei = eels[k0 + 8 * i];
            #pragma unroll
            for (int j = 0; j < 4; ++j) {
                float dd = __fsub_rn(__fadd_rn(xxv[j], eei), __fmul_rn(2.f, acc[j][i]));
                if (dd < dmin[j]) { dmin[j] = dd; idxv[j] = k0 + 8 * i; }
            }
        }
        __syncthreads();   // drains gll vmcnt + releases buffer cur
    }

    // cross-lane argmin over the 8 lanes_k (tid bits 0-2), first-occurrence ties
    #pragma unroll
    for (int j = 0; j < 4; ++j) {
        float d = dmin[j]; int ix = idxv[j];
        #pragma unroll
        for (int s = 1; s < 8; s <<= 1) {
            float od = __shfl_xor(d, s, 64);
            int oi = __shfl_xor(ix, s, 64);
            if (od < d || (od == d && oi < ix)) { d = od; ix = oi; }
        }
        idxv[j] = ix;
    }

    // outputs: each lane handles its 4 px over c-slice (tid&7)*8..+7
    int cs = (tid & 7) * 8;
    float lsum = 0.f;
    #pragma unroll
    for (int j = 0; j < 4; ++j) {
        int px = (tid >> 3) + 32 * j;
        int ix = idxv[j];
        const float4* eg = reinterpret_cast<const float4*>(e + (size_t)ix * CDIM + cs);
        float4 q0 = eg[0], q1 = eg[1];
        const float* xr = &xls[px * EST + cs];
        float* oq = out + OFF_Q + (size_t)b * CDIM * HWD + hw0 + px;
        oq[(size_t)(cs + 0) * HWD] = q0.x;
        oq[(size_t)(cs + 1) * HWD] = q0.y;
        oq[(size_t)(cs + 2) * HWD] = q0.z;
        oq[(size_t)(cs + 3) * HWD] = q0.w;
        oq[(size_t)(cs + 4) * HWD] = q1.x;
        oq[(size_t)(cs + 5) * HWD] = q1.y;
        oq[(size_t)(cs + 6) * HWD] = q1.z;
        oq[(size_t)(cs + 7) * HWD] = q1.w;
        float t;
        t = q0.x - xr[0]; lsum = __fmaf_rn(t, t, lsum);
        t = q0.y - xr[1]; lsum = __fmaf_rn(t, t, lsum);
        t = q0.z - xr[2]; lsum = __fmaf_rn(t, t, lsum);
        t = q0.w - xr[3]; lsum = __fmaf_rn(t, t, lsum);
        t = q1.x - xr[4]; lsum = __fmaf_rn(t, t, lsum);
        t = q1.y - xr[5]; lsum = __fmaf_rn(t, t, lsum);
        t = q1.z - xr[6]; lsum = __fmaf_rn(t, t, lsum);
        t = q1.w - xr[7]; lsum = __fmaf_rn(t, t, lsum);
    }
    if ((tid & 7) == 0) {
        #pragma unroll
        for (int j = 0; j < 4; ++j) {
            int px = (tid >> 3) + 32 * j;
            float fidx = (float)idxv[j];
            out[OFF_ENC + p0 + px] = fidx;
            out[OFF_CODES + p0 + px] = fidx;
            atomicAdd(&counts[idxv[j]], 1.0f);
        }
    }
    #pragma unroll
    for (int off = 32; off > 0; off >>= 1) lsum += __shfl_down(lsum, off, 64);
    if ((tid & 63) == 0) atomicAdd(loss_acc, lsum);
}

__global__ void finalize_kernel(const float* __restrict__ loss_acc,
                                const float* __restrict__ counts,
                                float* __restrict__ out) {
    __shared__ float red[8];
    int t = threadIdx.x;  // 512 threads
    float pr = counts[t] * (1.0f / (float)NPIX);
    float term = pr * logf(pr + 1e-10f);
    #pragma unroll
    for (int off = 32; off > 0; off >>= 1) term += __shfl_down(term, off, 64);
    if ((t & 63) == 0) red[t >> 6] = term;
    __syncthreads();
    if (t == 0) {
        float s = 0.f;
        #pragma unroll
        for (int i = 0; i < 8; ++i) s += red[i];
        out[OFF_PERP] = expf(-s);
        out[0] = 0.25f * loss_acc[0] * (1.0f / (float)NELEM);
    }
}

extern "C" void kernel_launch(void* const* d_in, const int* in_sizes, int n_in,
                              void* d_out, int out_size, void* d_ws, size_t ws_size,
                              hipStream_t stream) {
    const float* in = (const float*)d_in[0];
    const float* e = (const float*)d_in[1];
    float* out = (float*)d_out;
    float* wsf = (float*)d_ws;
    float* loss_acc = wsf + 0;
    float* counts = wsf + 64;
    float* ee = wsf + 576;

    hipMemsetAsync(d_ws, 0, 2304, stream);  // loss_acc + counts
    ee_kernel<<<1, 512, 0, stream>>>(e, ee);
    vq_main<<<NPIX / PXB, BLK, 0, stream>>>(in, e, ee, loss_acc, counts, out);
    finalize_kernel<<<1, 512, 0, stream>>>(loss_acc, counts, out);
}